// Round 1
// baseline (529.542 us; speedup 1.0000x reference)
//
#include <hip/hip_runtime.h>
#include <math.h>

#define BATCH 8
#define NN 2048
#define FIN 256
#define FOUT 64
#define ALPHA 0.2f
#define NEG_BIG -9000000000000000.0f

// ---------------------------------------------------------------------------
// Kernel A: h = x @ W  (per-row), e_l = h @ a_left, e_r = h @ a_right
// 256 threads = 4 waves; each wave handles 4 rows (16 rows/block).
// x rows staged in LDS (coalesced float4), W read coalesced (L1/L2-hot).
// ---------------------------------------------------------------------------
__global__ __launch_bounds__(256) void gat_h_kernel(
    const float* __restrict__ x, const float* __restrict__ W,
    const float* __restrict__ a, float* __restrict__ h,
    float* __restrict__ el, float* __restrict__ er) {
  __shared__ float xs[16][FIN];  // 16 KB
  const int t = threadIdx.x;
  const int wv = t >> 6;
  const int lane = t & 63;
  const int rowBase = blockIdx.x * 16;

  // stage 4 rows per wave: 64 lanes x float4 = 256 floats per row
  #pragma unroll
  for (int r = 0; r < 4; ++r) {
    int row = rowBase + wv * 4 + r;
    float4 v = ((const float4*)(x + (size_t)row * FIN))[lane];
    *(float4*)&xs[wv * 4 + r][lane * 4] = v;
  }
  __syncthreads();

  const int o = lane;
  float acc0 = 0.f, acc1 = 0.f, acc2 = 0.f, acc3 = 0.f;
  #pragma unroll 4
  for (int i = 0; i < FIN; ++i) {
    float wval = W[i * FOUT + o];       // coalesced 256B across lanes
    acc0 += xs[wv * 4 + 0][i] * wval;   // LDS broadcast (uniform addr)
    acc1 += xs[wv * 4 + 1][i] * wval;
    acc2 += xs[wv * 4 + 2][i] * wval;
    acc3 += xs[wv * 4 + 3][i] * wval;
  }

  const float aL = a[o];
  const float aR = a[FOUT + o];
  float accs[4] = {acc0, acc1, acc2, acc3};
  #pragma unroll
  for (int r = 0; r < 4; ++r) {
    int row = rowBase + wv * 4 + r;
    h[(size_t)row * FOUT + o] = accs[r];
    float vl = accs[r] * aL;
    float vr = accs[r] * aR;
    #pragma unroll
    for (int off = 32; off; off >>= 1) {
      vl += __shfl_xor(vl, off);
      vr += __shfl_xor(vr, off);
    }
    if (lane == 0) { el[row] = vl; er[row] = vr; }
  }
}

// ---------------------------------------------------------------------------
// Kernel B: flash-style masked softmax + attn@h + ELU.
// Block = 256 threads (4 waves), handles 16 n-rows of one batch.
// m-tiles of 64: h tile (64x64 f32) staged in LDS, online max/sum per row.
// Lane o owns output feature o; weights broadcast via per-wave LDS row.
// ---------------------------------------------------------------------------
__global__ __launch_bounds__(256) void gat_attn_kernel(
    const int* __restrict__ adj, const float* __restrict__ h,
    const float* __restrict__ el, const float* __restrict__ er,
    float* __restrict__ out) {
  __shared__ float hs[64][FOUT];   // 16 KB
  __shared__ float ers[64];
  __shared__ float wbuf[4][64];    // per-wave weight broadcast row

  const int t = threadIdx.x;
  const int wv = t >> 6;
  const int lane = t & 63;
  const int o = lane;
  const int b = blockIdx.x >> 7;            // 128 blocks per batch
  const int n0 = (blockIdx.x & 127) * 16;

  const size_t adjB = (size_t)b * NN * NN;
  const float* hB = h + (size_t)b * NN * FOUT;
  const float* erB = er + b * NN;

  int rowN[4];
  float eL[4], M[4], S[4], acc[4];
  #pragma unroll
  for (int r = 0; r < 4; ++r) {
    int n = n0 + wv * 4 + r;
    rowN[r] = n;
    eL[r] = el[b * NN + n];
    M[r] = NEG_BIG;
    S[r] = 0.f;
    acc[r] = 0.f;
  }

  for (int m0 = 0; m0 < NN; m0 += 64) {
    // stage h tile: 64 rows x 64 cols, 256 threads x 4 float4
    {
      int col4 = (t & 15) * 4;
      int rbase = t >> 4;  // 0..15
      #pragma unroll
      for (int p = 0; p < 4; ++p) {
        int mr = rbase + p * 16;
        float4 v = *(const float4*)(hB + (size_t)(m0 + mr) * FOUT + col4);
        *(float4*)&hs[mr][col4] = v;
      }
      if (t < 64) ers[t] = erB[m0 + t];
    }
    __syncthreads();

    // prefetch adj for my wave's 4 rows (coalesced 256B each)
    int av[4];
    #pragma unroll
    for (int r = 0; r < 4; ++r)
      av[r] = adj[adjB + (size_t)rowN[r] * NN + m0 + lane];

    #pragma unroll
    for (int r = 0; r < 4; ++r) {
      float e = eL[r] + ers[lane];
      e = e > 0.f ? e : ALPHA * e;
      float s = (av[r] > 0) ? e : NEG_BIG;
      // wave-wide max of this chunk
      float cm = s;
      #pragma unroll
      for (int off = 32; off; off >>= 1) cm = fmaxf(cm, __shfl_xor(cm, off));
      float Mnew = fmaxf(M[r], cm);
      float w = (av[r] > 0) ? __expf(e - Mnew) : 0.f;
      // wave-wide sum of weights
      float sw = w;
      #pragma unroll
      for (int off = 32; off; off >>= 1) sw += __shfl_xor(sw, off);
      float scale = __expf(M[r] - Mnew);
      S[r] = S[r] * scale + sw;
      float a4 = acc[r] * scale;
      M[r] = Mnew;
      wbuf[wv][lane] = w;  // same-wave LDS write->read: in-order DS pipeline
      #pragma unroll
      for (int mp = 0; mp < 64; mp += 4) {
        float4 w4 = *(const float4*)&wbuf[wv][mp];  // uniform addr: broadcast
        a4 += w4.x * hs[mp + 0][o];
        a4 += w4.y * hs[mp + 1][o];
        a4 += w4.z * hs[mp + 2][o];
        a4 += w4.w * hs[mp + 3][o];
      }
      acc[r] = a4;
    }
    __syncthreads();
  }

  // epilogue: normalize + ELU, coalesced store
  #pragma unroll
  for (int r = 0; r < 4; ++r) {
    float hp = acc[r] / S[r];
    float res = hp > 0.f ? hp : expm1f(hp);
    out[((size_t)b * NN + rowN[r]) * FOUT + o] = res;
  }
}

extern "C" void kernel_launch(void* const* d_in, const int* in_sizes, int n_in,
                              void* d_out, int out_size, void* d_ws, size_t ws_size,
                              hipStream_t stream) {
  const float* x   = (const float*)d_in[0];
  const int*   adj = (const int*)d_in[1];
  const float* W   = (const float*)d_in[2];
  const float* a   = (const float*)d_in[3];
  float* out = (float*)d_out;

  // workspace layout: h (4 MB) | el (64 KB) | er (64 KB)
  float* h  = (float*)d_ws;
  float* el = h + (size_t)BATCH * NN * FOUT;
  float* er = el + (size_t)BATCH * NN;

  dim3 blk(256);
  dim3 grdA((BATCH * NN) / 16);   // 1024 blocks
  hipLaunchKernelGGL(gat_h_kernel, grdA, blk, 0, stream, x, W, a, h, el, er);

  dim3 grdB(BATCH * (NN / 16));   // 1024 blocks
  hipLaunchKernelGGL(gat_attn_kernel, grdB, blk, 0, stream, adj, h, el, er, out);
}

// Round 2
// 61.185 us; speedup vs baseline: 8.6548x; 8.6548x over previous
//
#include <hip/hip_runtime.h>
#include <math.h>

#define BATCH 8
#define NN 2048
#define FIN 256
#define FOUT 64
#define ALPHA 0.2f

typedef __attribute__((ext_vector_type(8))) short bf16x8;
typedef __attribute__((ext_vector_type(4))) float f32x4;

static __device__ __forceinline__ unsigned short f2bf(float f) {
  unsigned int u = __float_as_uint(f);
  u += 0x7fffu + ((u >> 16) & 1u);
  return (unsigned short)(u >> 16);
}
static __device__ __forceinline__ float bf2f(unsigned short h) {
  return __uint_as_float(((unsigned int)h) << 16);
}
static __device__ __forceinline__ void gload16(const void* g, void* l) {
  __builtin_amdgcn_global_load_lds(
      (const __attribute__((address_space(1))) unsigned int*)g,
      (__attribute__((address_space(3))) unsigned int*)l, 16, 0, 0);
}

// ---------------------------------------------------------------------------
// K1: h = x@W via MFMA (hi/lo bf16 split for fp32-grade h), el/er via shuffle
// reduce, then emit per-64-row "staging images" of h (hi/lo planes) in the
// exact (pre-swizzled) LDS layout K2's ds_read_b128 B-fragments want.
// Grid: 256 blocks x 256 thr (4 waves x 16 rows). LDS: 64KB (W planes, then
// aliased as the 16KB image).
// ---------------------------------------------------------------------------
__global__ __launch_bounds__(256) void k1_h(
    const float* __restrict__ x, const float* __restrict__ W,
    const float* __restrict__ a, float* __restrict__ el,
    float* __restrict__ er, unsigned char* __restrict__ hS) {
  __shared__ __align__(16) unsigned short lds[32768];  // 64 KB
  const int t = threadIdx.x;
  const int wv = t >> 6;
  const int l = t & 63;
  const int l15 = l & 15;
  const int kg = l >> 4;

  // phase 0: stage W as bf16 hi/lo planes, XOR-swizzled so K1 frag reads are
  // ~conflict-free: u16 idx = plane*16384 + o*256 + ((k>>3)^(o&7))*8 + (k&7)
  {
    const float4* W4 = (const float4*)W;
    #pragma unroll
    for (int i = 0; i < 16; ++i) {
      int f = t + i * 256;            // float4 index, 0..4095
      float4 v = W4[f];
      int k = f >> 4;                 // W row 0..255
      int ob = (f & 15) * 4;
      float vv[4] = {v.x, v.y, v.z, v.w};
      #pragma unroll
      for (int c = 0; c < 4; ++c) {
        int o = ob + c;
        unsigned short hi = f2bf(vv[c]);
        unsigned short lo = f2bf(vv[c] - bf2f(hi));
        int idx = o * 256 + (((k >> 3) ^ (o & 7)) * 8) + (k & 7);
        lds[idx] = hi;
        lds[16384 + idx] = lo;
      }
    }
  }
  __syncthreads();

  const int row = blockIdx.x * 64 + wv * 16 + l15;
  f32x4 acc[4] = {{0.f,0.f,0.f,0.f},{0.f,0.f,0.f,0.f},
                  {0.f,0.f,0.f,0.f},{0.f,0.f,0.f,0.f}};
  const float* xrow = x + (size_t)row * FIN;

  #pragma unroll
  for (int ks = 0; ks < 8; ++ks) {
    int k0 = ks * 32;
    float4 xa = *(const float4*)(xrow + k0 + kg * 8);
    float4 xb = *(const float4*)(xrow + k0 + kg * 8 + 4);
    float xv[8] = {xa.x, xa.y, xa.z, xa.w, xb.x, xb.y, xb.z, xb.w};
    bf16x8 ahi, alo;
    #pragma unroll
    for (int j = 0; j < 8; ++j) {
      unsigned short hi = f2bf(xv[j]);
      unsigned short lo = f2bf(xv[j] - bf2f(hi));
      ahi[j] = (short)hi;
      alo[j] = (short)lo;
    }
    int kgidx = ks * 4 + kg;
    #pragma unroll
    for (int ot = 0; ot < 4; ++ot) {
      int o = ot * 16 + l15;
      int base = o * 256 + ((kgidx ^ (o & 7)) * 8);
      bf16x8 bhi = *(const bf16x8*)&lds[base];
      bf16x8 blo = *(const bf16x8*)&lds[16384 + base];
      acc[ot] = __builtin_amdgcn_mfma_f32_16x16x32_bf16(ahi, bhi, acc[ot], 0, 0, 0);
      acc[ot] = __builtin_amdgcn_mfma_f32_16x16x32_bf16(ahi, blo, acc[ot], 0, 0, 0);
      acc[ot] = __builtin_amdgcn_mfma_f32_16x16x32_bf16(alo, bhi, acc[ot], 0, 0, 0);
    }
  }

  // el/er: reduce across the 16 col-lanes (same kg group)
  float aLv[4], aRv[4];
  #pragma unroll
  for (int ot = 0; ot < 4; ++ot) {
    aLv[ot] = a[ot * 16 + l15];
    aRv[ot] = a[64 + ot * 16 + l15];
  }
  #pragma unroll
  for (int jj = 0; jj < 4; ++jj) {
    float pl = 0.f, pr = 0.f;
    #pragma unroll
    for (int ot = 0; ot < 4; ++ot) {
      pl += acc[ot][jj] * aLv[ot];
      pr += acc[ot][jj] * aRv[ot];
    }
    #pragma unroll
    for (int s = 1; s < 16; s <<= 1) {
      pl += __shfl_xor(pl, s);
      pr += __shfl_xor(pr, s);
    }
    if (l15 == 0) {
      int grow = blockIdx.x * 64 + wv * 16 + kg * 4 + jj;
      el[grow] = pl;
      er[grow] = pr;
    }
  }

  // phase 2: hi/lo split of h, scatter into the image layout (alias lds):
  // u16 idx = ((ks2*2+plane)*64 + o)*32 + (kg2 ^ ((o>>1)&3))*8 + j
  // where m_loc = ks2*32 + kg2*8 + j
  __syncthreads();
  #pragma unroll
  for (int ot = 0; ot < 4; ++ot) {
    int o = ot * 16 + l15;
    int xorv = (o >> 1) & 3;
    #pragma unroll
    for (int jj = 0; jj < 4; ++jj) {
      int m_loc = wv * 16 + kg * 4 + jj;
      int ks2 = m_loc >> 5;
      int kg2 = (m_loc >> 3) & 3;
      int j = m_loc & 7;
      int kgp = kg2 ^ xorv;
      float v = acc[ot][jj];
      unsigned short hi = f2bf(v);
      unsigned short lo = f2bf(v - bf2f(hi));
      int base = ((ks2 * 2 + 0) * 64 + o) * 32 + kgp * 8 + j;
      lds[base] = hi;
      lds[base + 2048] = lo;  // plane stride = 64*32 u16
    }
  }
  __syncthreads();

  // dump 16KB image contiguously to global
  {
    const uint4* src = (const uint4*)(const void*)lds;
    uint4* dst = (uint4*)(hS + (size_t)blockIdx.x * 16384);
    #pragma unroll
    for (int i = 0; i < 4; ++i) dst[t + i * 256] = src[t + i * 256];
  }
}

// ---------------------------------------------------------------------------
// K2: masked-softmax attention as MFMA GEMM, no max-tracking (scores bounded).
// Grid: 512 blocks x 128 thr (2 waves x 16 rows = 32 rows/block, 2 blocks/CU).
// Per 64-m chunk: double-buffered global_load_lds of the 16KB h image
// (pre-swizzled in global), adj/er register prefetch, 16 MFMA (hi+lo planes).
// ---------------------------------------------------------------------------
__global__ __launch_bounds__(128) void k2_attn(
    const int* __restrict__ adj, const unsigned char* __restrict__ hS,
    const float* __restrict__ el, const float* __restrict__ er,
    float* __restrict__ out) {
  __shared__ __align__(1024) unsigned char buf[2][16384];
  const int t = threadIdx.x;
  const int wv = t >> 6;
  const int l = t & 63;
  const int l15 = l & 15;
  const int kg = l >> 4;

  // XCD-bijective swizzle: 512 blocks, 64/XCD -> each XCD sees one batch
  int bid = blockIdx.x;
  int swz = (bid & 7) * 64 + (bid >> 3);
  int b = swz >> 6;
  int n0 = (swz & 63) * 32;
  const int nrow = n0 + wv * 16 + l15;

  const float eL = el[b * NN + nrow];
  const float* erb = er + b * NN;
  const int* arow = adj + (size_t)b * NN * NN + (size_t)nrow * NN;
  const unsigned char* hSb = hS + (size_t)b * 32 * 16384;

  const int laneoff = l15 * 64 + ((kg ^ ((l >> 1) & 3)) * 16);

  f32x4 acc[4] = {{0.f,0.f,0.f,0.f},{0.f,0.f,0.f,0.f},
                  {0.f,0.f,0.f,0.f},{0.f,0.f,0.f,0.f}};
  float Sacc = 0.f;

  // prologue: stage chunk 0, prefetch adj/er chunk 0
  #pragma unroll
  for (int s = 0; s < 8; ++s) {
    int seg = wv * 8 + s;
    gload16(hSb + seg * 1024 + l * 16, &buf[0][seg * 1024]);
  }
  int4 av[4];
  float4 ev[4];
  #pragma unroll
  for (int ksx = 0; ksx < 2; ++ksx) {
    av[ksx * 2 + 0] = *(const int4*)(arow + ksx * 32 + kg * 8);
    av[ksx * 2 + 1] = *(const int4*)(arow + ksx * 32 + kg * 8 + 4);
    ev[ksx * 2 + 0] = *(const float4*)(erb + ksx * 32 + kg * 8);
    ev[ksx * 2 + 1] = *(const float4*)(erb + ksx * 32 + kg * 8 + 4);
  }
  __syncthreads();

  for (int tc = 0; tc < 32; ++tc) {
    const unsigned char* cur = buf[tc & 1];
    int4 avn[4];
    float4 evn[4];
    if (tc < 31) {
      const unsigned char* src = hSb + (size_t)(tc + 1) * 16384;
      unsigned char* dstb = buf[(tc + 1) & 1];
      #pragma unroll
      for (int s = 0; s < 8; ++s) {
        int seg = wv * 8 + s;
        gload16(src + seg * 1024 + l * 16, dstb + seg * 1024);
      }
      int mb = (tc + 1) * 64;
      #pragma unroll
      for (int ksx = 0; ksx < 2; ++ksx) {
        avn[ksx * 2 + 0] = *(const int4*)(arow + mb + ksx * 32 + kg * 8);
        avn[ksx * 2 + 1] = *(const int4*)(arow + mb + ksx * 32 + kg * 8 + 4);
        evn[ksx * 2 + 0] = *(const float4*)(erb + mb + ksx * 32 + kg * 8);
        evn[ksx * 2 + 1] = *(const float4*)(erb + mb + ksx * 32 + kg * 8 + 4);
      }
    }

    #pragma unroll
    for (int ks = 0; ks < 2; ++ks) {
      int aarr[8] = {av[ks*2].x, av[ks*2].y, av[ks*2].z, av[ks*2].w,
                     av[ks*2+1].x, av[ks*2+1].y, av[ks*2+1].z, av[ks*2+1].w};
      float earr[8] = {ev[ks*2].x, ev[ks*2].y, ev[ks*2].z, ev[ks*2].w,
                       ev[ks*2+1].x, ev[ks*2+1].y, ev[ks*2+1].z, ev[ks*2+1].w};
      bf16x8 af;
      #pragma unroll
      for (int j = 0; j < 8; ++j) {
        float e = eL + earr[j];
        e = fmaxf(e, ALPHA * e);          // leaky relu
        float w = (aarr[j] > 0) ? __expf(e) : 0.f;
        unsigned short hb = f2bf(w);
        af[j] = (short)hb;
        Sacc += bf2f(hb);                 // denominator from the SAME rounded w
      }
      #pragma unroll
      for (int ot = 0; ot < 4; ++ot) {
        const unsigned char* p = cur + ks * 8192 + ot * 1024 + laneoff;
        bf16x8 bhi = *(const bf16x8*)p;
        bf16x8 blo = *(const bf16x8*)(p + 4096);
        acc[ot] = __builtin_amdgcn_mfma_f32_16x16x32_bf16(af, bhi, acc[ot], 0, 0, 0);
        acc[ot] = __builtin_amdgcn_mfma_f32_16x16x32_bf16(af, blo, acc[ot], 0, 0, 0);
      }
    }

    if (tc < 31) {
      #pragma unroll
      for (int i = 0; i < 4; ++i) { av[i] = avn[i]; ev[i] = evn[i]; }
    }
    __syncthreads();
  }

  // epilogue: S across kg groups, normalize, ELU, store
  float Sred = Sacc + __shfl_xor(Sacc, 16);
  Sred += __shfl_xor(Sred, 32);
  float Sj[4];
  #pragma unroll
  for (int jj = 0; jj < 4; ++jj) Sj[jj] = __shfl(Sred, kg * 4 + jj);
  #pragma unroll
  for (int ot = 0; ot < 4; ++ot) {
    #pragma unroll
    for (int jj = 0; jj < 4; ++jj) {
      float v = acc[ot][jj] / Sj[jj];
      float res = v > 0.f ? v : expm1f(v);
      out[((size_t)b * NN + n0 + wv * 16 + kg * 4 + jj) * FOUT + ot * 16 + l15] = res;
    }
  }
}

extern "C" void kernel_launch(void* const* d_in, const int* in_sizes, int n_in,
                              void* d_out, int out_size, void* d_ws, size_t ws_size,
                              hipStream_t stream) {
  const float* x   = (const float*)d_in[0];
  const int*   adj = (const int*)d_in[1];
  const float* W   = (const float*)d_in[2];
  const float* a   = (const float*)d_in[3];
  float* out = (float*)d_out;

  // ws layout: hS images (8*32*16KB = 4MB) | el (64KB) | er (64KB)
  unsigned char* hS = (unsigned char*)d_ws;
  float* el = (float*)(hS + (size_t)BATCH * 32 * 16384);
  float* er = el + BATCH * NN;

  hipLaunchKernelGGL(k1_h, dim3(256), dim3(256), 0, stream, x, W, a, el, er, hS);
  hipLaunchKernelGGL(k2_attn, dim3(512), dim3(128), 0, stream, adj, hS, el, er, out);
}

// Round 3
// 52.573 us; speedup vs baseline: 10.0724x; 1.1638x over previous
//
#include <hip/hip_runtime.h>
#include <math.h>

#define BATCH 8
#define NN 2048
#define FIN 256
#define FOUT 64
#define ALPHA 0.2f

typedef __attribute__((ext_vector_type(8))) short bf16x8;
typedef __attribute__((ext_vector_type(4))) float f32x4;

static __device__ __forceinline__ unsigned short f2bf(float f) {
  unsigned int u = __float_as_uint(f);
  u += 0x7fffu + ((u >> 16) & 1u);
  return (unsigned short)(u >> 16);
}
static __device__ __forceinline__ float bf2f(unsigned short h) {
  return __uint_as_float(((unsigned int)h) << 16);
}
static __device__ __forceinline__ void gload16(const void* g, void* l) {
  __builtin_amdgcn_global_load_lds(
      (const __attribute__((address_space(1))) unsigned int*)g,
      (__attribute__((address_space(3))) unsigned int*)l, 16, 0, 0);
}

// ---------------------------------------------------------------------------
// K1: h = x@W via MFMA (hi/lo bf16 split for fp32-grade h), el/er via shuffle
// reduce, then emit per-64-row "staging images" of h (hi/lo planes) in the
// exact (pre-swizzled) LDS layout K2's ds_read_b128 B-fragments want.
// Grid: 256 blocks x 256 thr (4 waves x 16 rows). LDS: 64KB.  (unchanged)
// ---------------------------------------------------------------------------
__global__ __launch_bounds__(256) void k1_h(
    const float* __restrict__ x, const float* __restrict__ W,
    const float* __restrict__ a, float* __restrict__ el,
    float* __restrict__ er, unsigned char* __restrict__ hS) {
  __shared__ __align__(16) unsigned short lds[32768];  // 64 KB
  const int t = threadIdx.x;
  const int wv = t >> 6;
  const int l = t & 63;
  const int l15 = l & 15;
  const int kg = l >> 4;

  // phase 0: stage W as bf16 hi/lo planes, XOR-swizzled:
  // u16 idx = plane*16384 + o*256 + ((k>>3)^(o&7))*8 + (k&7)
  {
    const float4* W4 = (const float4*)W;
    #pragma unroll
    for (int i = 0; i < 16; ++i) {
      int f = t + i * 256;            // float4 index, 0..4095
      float4 v = W4[f];
      int k = f >> 4;                 // W row 0..255
      int ob = (f & 15) * 4;
      float vv[4] = {v.x, v.y, v.z, v.w};
      #pragma unroll
      for (int c = 0; c < 4; ++c) {
        int o = ob + c;
        unsigned short hi = f2bf(vv[c]);
        unsigned short lo = f2bf(vv[c] - bf2f(hi));
        int idx = o * 256 + (((k >> 3) ^ (o & 7)) * 8) + (k & 7);
        lds[idx] = hi;
        lds[16384 + idx] = lo;
      }
    }
  }
  __syncthreads();

  const int row = blockIdx.x * 64 + wv * 16 + l15;
  f32x4 acc[4] = {{0.f,0.f,0.f,0.f},{0.f,0.f,0.f,0.f},
                  {0.f,0.f,0.f,0.f},{0.f,0.f,0.f,0.f}};
  const float* xrow = x + (size_t)row * FIN;

  #pragma unroll
  for (int ks = 0; ks < 8; ++ks) {
    int k0 = ks * 32;
    float4 xa = *(const float4*)(xrow + k0 + kg * 8);
    float4 xb = *(const float4*)(xrow + k0 + kg * 8 + 4);
    float xv[8] = {xa.x, xa.y, xa.z, xa.w, xb.x, xb.y, xb.z, xb.w};
    bf16x8 ahi, alo;
    #pragma unroll
    for (int j = 0; j < 8; ++j) {
      unsigned short hi = f2bf(xv[j]);
      unsigned short lo = f2bf(xv[j] - bf2f(hi));
      ahi[j] = (short)hi;
      alo[j] = (short)lo;
    }
    int kgidx = ks * 4 + kg;
    #pragma unroll
    for (int ot = 0; ot < 4; ++ot) {
      int o = ot * 16 + l15;
      int base = o * 256 + ((kgidx ^ (o & 7)) * 8);
      bf16x8 bhi = *(const bf16x8*)&lds[base];
      bf16x8 blo = *(const bf16x8*)&lds[16384 + base];
      acc[ot] = __builtin_amdgcn_mfma_f32_16x16x32_bf16(ahi, bhi, acc[ot], 0, 0, 0);
      acc[ot] = __builtin_amdgcn_mfma_f32_16x16x32_bf16(ahi, blo, acc[ot], 0, 0, 0);
      acc[ot] = __builtin_amdgcn_mfma_f32_16x16x32_bf16(alo, bhi, acc[ot], 0, 0, 0);
    }
  }

  // el/er: reduce across the 16 col-lanes (same kg group)
  float aLv[4], aRv[4];
  #pragma unroll
  for (int ot = 0; ot < 4; ++ot) {
    aLv[ot] = a[ot * 16 + l15];
    aRv[ot] = a[64 + ot * 16 + l15];
  }
  #pragma unroll
  for (int jj = 0; jj < 4; ++jj) {
    float pl = 0.f, pr = 0.f;
    #pragma unroll
    for (int ot = 0; ot < 4; ++ot) {
      pl += acc[ot][jj] * aLv[ot];
      pr += acc[ot][jj] * aRv[ot];
    }
    #pragma unroll
    for (int s = 1; s < 16; s <<= 1) {
      pl += __shfl_xor(pl, s);
      pr += __shfl_xor(pr, s);
    }
    if (l15 == 0) {
      int grow = blockIdx.x * 64 + wv * 16 + kg * 4 + jj;
      el[grow] = pl;
      er[grow] = pr;
    }
  }

  // phase 2: hi/lo split of h, scatter into the image layout (alias lds):
  // u16 idx = ((ks2*2+plane)*64 + o)*32 + (kg2 ^ ((o>>1)&3))*8 + j
  __syncthreads();
  #pragma unroll
  for (int ot = 0; ot < 4; ++ot) {
    int o = ot * 16 + l15;
    int xorv = (o >> 1) & 3;
    #pragma unroll
    for (int jj = 0; jj < 4; ++jj) {
      int m_loc = wv * 16 + kg * 4 + jj;
      int ks2 = m_loc >> 5;
      int kg2 = (m_loc >> 3) & 3;
      int j = m_loc & 7;
      int kgp = kg2 ^ xorv;
      float v = acc[ot][jj];
      unsigned short hi = f2bf(v);
      unsigned short lo = f2bf(v - bf2f(hi));
      int base = ((ks2 * 2 + 0) * 64 + o) * 32 + kgp * 8 + j;
      lds[base] = hi;
      lds[base + 2048] = lo;  // plane stride = 64*32 u16
    }
  }
  __syncthreads();

  // dump 16KB image contiguously to global
  {
    const uint4* src = (const uint4*)(const void*)lds;
    uint4* dst = (uint4*)(hS + (size_t)blockIdx.x * 16384);
    #pragma unroll
    for (int i = 0; i < 4; ++i) dst[t + i * 256] = src[t + i * 256];
  }
}

// ---------------------------------------------------------------------------
// K2: masked-softmax attention as MFMA GEMM, no max-tracking.
// Grid: 512 blocks x 256 thr. Wave pair p = wv>>1 handles m-half p (1024 m);
// within a pair, wave pw = wv&1 owns 16 rows. Each pair double-buffers its
// own 16KB h-image chunks (64KB LDS total -> 2 blocks/CU, 8 waves/CU).
// Partial acc/S combined across pairs via LDS at the end.
// ---------------------------------------------------------------------------
__global__ __launch_bounds__(256, 2) void k2_attn(
    const int* __restrict__ adj, const unsigned char* __restrict__ hS,
    const float* __restrict__ el, const float* __restrict__ er,
    float* __restrict__ out) {
  __shared__ __align__(1024) unsigned char buf[2][2][16384];
  const int t = threadIdx.x;
  const int wv = t >> 6;
  const int l = t & 63;
  const int l15 = l & 15;
  const int kg = l >> 4;
  const int pair = wv >> 1;   // which m-half
  const int pw = wv & 1;      // row sub-block within pair

  // XCD-bijective swizzle: 512 blocks, 64/XCD -> each XCD sees one batch
  int bid = blockIdx.x;
  int swz = (bid & 7) * 64 + (bid >> 3);
  int b = swz >> 6;
  int n0 = (swz & 63) * 32;
  const int nrow = n0 + pw * 16 + l15;

  const float eL = el[b * NN + nrow];
  const float* erp = er + b * NN + pair * 1024;
  const int* arow = adj + (size_t)b * NN * NN + (size_t)nrow * NN + pair * 1024;
  const unsigned char* hSb =
      hS + (size_t)b * 32 * 16384 + (size_t)pair * 16 * 16384;

  const int laneoff = l15 * 64 + ((kg ^ ((l >> 1) & 3)) * 16);

  f32x4 acc[4] = {{0.f,0.f,0.f,0.f},{0.f,0.f,0.f,0.f},
                  {0.f,0.f,0.f,0.f},{0.f,0.f,0.f,0.f}};
  float Sacc = 0.f;

  // prologue: stage chunk 0 of this pair's half, prefetch adj/er chunk 0
  #pragma unroll
  for (int s = 0; s < 8; ++s) {
    int seg = pw * 8 + s;
    gload16(hSb + seg * 1024 + l * 16, &buf[pair][0][seg * 1024]);
  }
  int4 av[4];
  float4 ev[4];
  #pragma unroll
  for (int ksx = 0; ksx < 2; ++ksx) {
    av[ksx * 2 + 0] = *(const int4*)(arow + ksx * 32 + kg * 8);
    av[ksx * 2 + 1] = *(const int4*)(arow + ksx * 32 + kg * 8 + 4);
    ev[ksx * 2 + 0] = *(const float4*)(erp + ksx * 32 + kg * 8);
    ev[ksx * 2 + 1] = *(const float4*)(erp + ksx * 32 + kg * 8 + 4);
  }
  __syncthreads();

  for (int tc = 0; tc < 16; ++tc) {
    const unsigned char* cur = &buf[pair][tc & 1][0];
    int4 avn[4];
    float4 evn[4];
    if (tc < 15) {
      const unsigned char* src = hSb + (size_t)(tc + 1) * 16384;
      unsigned char* dstb = &buf[pair][(tc + 1) & 1][0];
      #pragma unroll
      for (int s = 0; s < 8; ++s) {
        int seg = pw * 8 + s;
        gload16(src + seg * 1024 + l * 16, dstb + seg * 1024);
      }
      int mb = (tc + 1) * 64;
      #pragma unroll
      for (int ksx = 0; ksx < 2; ++ksx) {
        avn[ksx * 2 + 0] = *(const int4*)(arow + mb + ksx * 32 + kg * 8);
        avn[ksx * 2 + 1] = *(const int4*)(arow + mb + ksx * 32 + kg * 8 + 4);
        evn[ksx * 2 + 0] = *(const float4*)(erp + mb + ksx * 32 + kg * 8);
        evn[ksx * 2 + 1] = *(const float4*)(erp + mb + ksx * 32 + kg * 8 + 4);
      }
    }

    #pragma unroll
    for (int ks = 0; ks < 2; ++ks) {
      int aarr[8] = {av[ks*2].x, av[ks*2].y, av[ks*2].z, av[ks*2].w,
                     av[ks*2+1].x, av[ks*2+1].y, av[ks*2+1].z, av[ks*2+1].w};
      float earr[8] = {ev[ks*2].x, ev[ks*2].y, ev[ks*2].z, ev[ks*2].w,
                       ev[ks*2+1].x, ev[ks*2+1].y, ev[ks*2+1].z, ev[ks*2+1].w};
      bf16x8 af;
      #pragma unroll
      for (int j = 0; j < 8; ++j) {
        float e = eL + earr[j];
        e = fmaxf(e, ALPHA * e);          // leaky relu
        float w = (aarr[j] > 0) ? __expf(e) : 0.f;
        unsigned short hb = f2bf(w);
        af[j] = (short)hb;
        Sacc += bf2f(hb);                 // denominator from the SAME rounded w
      }
      #pragma unroll
      for (int ot = 0; ot < 4; ++ot) {
        const unsigned char* p = cur + ks * 8192 + ot * 1024 + laneoff;
        bf16x8 bhi = *(const bf16x8*)p;
        bf16x8 blo = *(const bf16x8*)(p + 4096);
        acc[ot] = __builtin_amdgcn_mfma_f32_16x16x32_bf16(af, bhi, acc[ot], 0, 0, 0);
        acc[ot] = __builtin_amdgcn_mfma_f32_16x16x32_bf16(af, blo, acc[ot], 0, 0, 0);
      }
    }

    if (tc < 15) {
      #pragma unroll
      for (int i = 0; i < 4; ++i) { av[i] = avn[i]; ev[i] = evn[i]; }
    }
    __syncthreads();
  }

  // S partial: reduce across kg groups within this wave (replicated over kg)
  float Sred = Sacc + __shfl_xor(Sacc, 16);
  Sred += __shfl_xor(Sred, 32);

  // cross-pair combine via LDS: pair-1 waves publish {acc[16], Sred},
  // pair-0 waves (same rows) add them in. slot stride 96 B (16B-aligned).
  {
    unsigned char* cb = &buf[0][0][0];
    const int slot = pw * 64 + l;
    if (pair == 1) {
      float* dst = (float*)(cb + slot * 96);
      *(f32x4*)(dst + 0)  = acc[0];
      *(f32x4*)(dst + 4)  = acc[1];
      *(f32x4*)(dst + 8)  = acc[2];
      *(f32x4*)(dst + 12) = acc[3];
      dst[16] = Sred;
    }
    __syncthreads();
    if (pair == 1) return;
    const float* src = (const float*)(cb + slot * 96);
    #pragma unroll
    for (int ot = 0; ot < 4; ++ot) {
      f32x4 o4 = *(const f32x4*)(src + ot * 4);
      acc[ot] += o4;
    }
    Sred += src[16];
  }

  // epilogue (pair 0 only): normalize, ELU, store
  float Sj[4];
  #pragma unroll
  for (int jj = 0; jj < 4; ++jj) Sj[jj] = __shfl(Sred, kg * 4 + jj);
  #pragma unroll
  for (int ot = 0; ot < 4; ++ot) {
    #pragma unroll
    for (int jj = 0; jj < 4; ++jj) {
      float v = acc[ot][jj] / Sj[jj];
      float res = v > 0.f ? v : expm1f(v);
      out[((size_t)b * NN + n0 + pw * 16 + kg * 4 + jj) * FOUT + ot * 16 + l15] = res;
    }
  }
}

extern "C" void kernel_launch(void* const* d_in, const int* in_sizes, int n_in,
                              void* d_out, int out_size, void* d_ws, size_t ws_size,
                              hipStream_t stream) {
  const float* x   = (const float*)d_in[0];
  const int*   adj = (const int*)d_in[1];
  const float* W   = (const float*)d_in[2];
  const float* a   = (const float*)d_in[3];
  float* out = (float*)d_out;

  // ws layout: hS images (8*32*16KB = 4MB) | el (64KB) | er (64KB)
  unsigned char* hS = (unsigned char*)d_ws;
  float* el = (float*)(hS + (size_t)BATCH * 32 * 16384);
  float* er = el + BATCH * NN;

  hipLaunchKernelGGL(k1_h, dim3(256), dim3(256), 0, stream, x, W, a, el, er, hS);
  hipLaunchKernelGGL(k2_attn, dim3(512), dim3(256), 0, stream, adj, hS, el, er, out);
}